// Round 1
// baseline (1763.406 us; speedup 1.0000x reference)
//
#include <hip/hip_runtime.h>
#include <math.h>

#define N_TOK 4096
#define DMODEL 512
#define NHEAD 4
#define HDIM 128
#define NBINS 32
#define BQ 64
#define BK 64

// ---------------------------------------------------------------- PE kernel
// pe[n, 0:256]  = interleave(sin(r*f_k), cos(r*f_k)), k=0..127
// pe[n, 256:512]= same with cols
__global__ __launch_bounds__(256) void pe_kernel(const int* __restrict__ rows,
                                                 const int* __restrict__ cols,
                                                 float* __restrict__ pe) {
    int n = blockIdx.x, t = threadIdx.x;
    float pos = (float)((t < 128) ? rows[n] : cols[n]);
    int k = t & 127;
    // freq = exp(-(log(10000)/256) * 2k)
    float freq = expf(-0.035977892078032f * (float)(2 * k));
    float ang = pos * freq;
    int base = n * DMODEL + ((t < 128) ? 0 : 256) + 2 * k;
    pe[base]     = sinf(ang);
    pe[base + 1] = cosf(ang);
}

// ---------------------------------------------------------------- GEMM: C = A @ W^T (+ addv)
// A: (4096,512) row-major, W: (512,512) row-major, C[n][j] = sum_k A[n][k]*W[j][k]
template <bool ADD>
__global__ __launch_bounds__(256) void gemm_aw(const float* __restrict__ A,
                                               const float* __restrict__ W,
                                               const float* __restrict__ addv,
                                               float* __restrict__ C) {
    const int n0 = blockIdx.x * 64;
    const int j0 = blockIdx.y * 64;
    __shared__ float As[64][68];
    __shared__ float Ws[64][68];
    const int t  = threadIdx.x;
    const int tx = t & 15, ty = t >> 4;
    const int lr = t >> 4;          // staging row 0..15
    const int lc = (t & 15) * 4;    // staging col 0..60
    float acc[4][4] = {};

    for (int k0 = 0; k0 < DMODEL; k0 += 64) {
        __syncthreads();
#pragma unroll
        for (int rr = 0; rr < 64; rr += 16) {
            *(float4*)&As[lr + rr][lc] = *(const float4*)&A[(size_t)(n0 + lr + rr) * DMODEL + k0 + lc];
            *(float4*)&Ws[lr + rr][lc] = *(const float4*)&W[(size_t)(j0 + lr + rr) * DMODEL + k0 + lc];
        }
        __syncthreads();
#pragma unroll 4
        for (int kk = 0; kk < 64; kk += 4) {
            float4 a[4], b[4];
#pragma unroll
            for (int ii = 0; ii < 4; ++ii) a[ii] = *(const float4*)&As[ty * 4 + ii][kk];
#pragma unroll
            for (int jj = 0; jj < 4; ++jj) b[jj] = *(const float4*)&Ws[tx * 4 + jj][kk];
#pragma unroll
            for (int ii = 0; ii < 4; ++ii)
#pragma unroll
                for (int jj = 0; jj < 4; ++jj)
                    acc[ii][jj] += a[ii].x * b[jj].x + a[ii].y * b[jj].y +
                                   a[ii].z * b[jj].z + a[ii].w * b[jj].w;
        }
    }
#pragma unroll
    for (int ii = 0; ii < 4; ++ii) {
        const int row = n0 + ty * 4 + ii;
        float4 r;
        r.x = acc[ii][0]; r.y = acc[ii][1]; r.z = acc[ii][2]; r.w = acc[ii][3];
        if (ADD) {
            const float4 av = *(const float4*)&addv[(size_t)row * DMODEL + j0 + tx * 4];
            r.x += av.x; r.y += av.y; r.z += av.z; r.w += av.w;
        }
        *(float4*)&C[(size_t)row * DMODEL + j0 + tx * 4] = r;
    }
}

// ---------------------------------------------------------------- flash attention with distance bias
// grid (N/BQ, H). One block = 64 query rows of one head. 256 threads.
__global__ __launch_bounds__(256) void attn_kernel(const float* __restrict__ Q,
                                                   const float* __restrict__ K,
                                                   const float* __restrict__ V,
                                                   const int* __restrict__ prows,
                                                   const int* __restrict__ pcols,
                                                   const float* __restrict__ dist_bias,
                                                   float* __restrict__ attn_out) {
    const int h  = blockIdx.y;
    const int n0 = blockIdx.x * BQ;
    __shared__ float Qs[BQ][HDIM];
    __shared__ float Ks[BK][HDIM];
    __shared__ float Vs[BK][HDIM];
    __shared__ float Ss[BQ][BK + 1];
    __shared__ float biasT[3043];
    __shared__ float mrow[BQ], lrow[BQ], arow[BQ];
    __shared__ int   qr[BQ], qc[BQ], kr[BK], kc[BK];
    const int t  = threadIdx.x;
    const int tx = t & 15, ty = t >> 4;

    // per-head bias LUT over s = dr^2 + dc^2 (0..3042)
    for (int idx = t; idx < 3043; idx += 256) {
        float d   = sqrtf((float)idx);
        int  bin  = (int)(log1pf(d) / 4.0529789877f * 31.0f);
        bin = bin > 31 ? 31 : bin;
        biasT[idx] = dist_bias[h * NBINS + bin];
    }
    for (int idx = t * 4; idx < BQ * HDIM; idx += 1024) {
        int r = idx >> 7, c = idx & 127;
        *(float4*)&Qs[r][c] = *(const float4*)&Q[(size_t)(n0 + r) * DMODEL + h * HDIM + c];
    }
    if (t < BQ) {
        qr[t] = prows[n0 + t]; qc[t] = pcols[n0 + t];
        mrow[t] = -1e30f; lrow[t] = 0.0f;
    }

    float acc[4][8] = {};
    const float scale = 0.08838834764831845f;  // 1/sqrt(128)

    for (int kb = 0; kb < N_TOK / BK; ++kb) {
        const int m0 = kb * BK;
        __syncthreads();   // protect Ks/Vs/Ss from previous iteration
        for (int idx = t * 4; idx < BK * HDIM; idx += 1024) {
            int r = idx >> 7, c = idx & 127;
            *(float4*)&Ks[r][c] = *(const float4*)&K[(size_t)(m0 + r) * DMODEL + h * HDIM + c];
            *(float4*)&Vs[r][c] = *(const float4*)&V[(size_t)(m0 + r) * DMODEL + h * HDIM + c];
        }
        if (t < BK) { kr[t] = prows[m0 + t]; kc[t] = pcols[m0 + t]; }
        __syncthreads();

        // phase 1: S = Q·K^T * scale + bias  (4x4 microtile per thread)
        {
            float s4[4][4] = {};
#pragma unroll 4
            for (int kk = 0; kk < HDIM; kk += 4) {
                float4 a[4], b[4];
#pragma unroll
                for (int ii = 0; ii < 4; ++ii) a[ii] = *(const float4*)&Qs[ty * 4 + ii][kk];
#pragma unroll
                for (int jj = 0; jj < 4; ++jj) b[jj] = *(const float4*)&Ks[tx * 4 + jj][kk];
#pragma unroll
                for (int ii = 0; ii < 4; ++ii)
#pragma unroll
                    for (int jj = 0; jj < 4; ++jj)
                        s4[ii][jj] += a[ii].x * b[jj].x + a[ii].y * b[jj].y +
                                      a[ii].z * b[jj].z + a[ii].w * b[jj].w;
            }
#pragma unroll
            for (int ii = 0; ii < 4; ++ii) {
                int i = ty * 4 + ii;
#pragma unroll
                for (int jj = 0; jj < 4; ++jj) {
                    int j  = tx * 4 + jj;
                    int dr = qr[i] - kr[j], dc = qc[i] - kc[j];
                    int s  = dr * dr + dc * dc;
                    Ss[i][j] = s4[ii][jj] * scale + biasT[s];
                }
            }
        }
        __syncthreads();

        // phase 2: online softmax per row (4 threads per row)
        {
            int row = t >> 2, l4 = t & 3;
            float mx = -1e30f;
            for (int j = l4 * 16; j < l4 * 16 + 16; ++j) mx = fmaxf(mx, Ss[row][j]);
            mx = fmaxf(mx, __shfl_xor(mx, 1, 4));
            mx = fmaxf(mx, __shfl_xor(mx, 2, 4));
            float mold = mrow[row];
            float mnew = fmaxf(mold, mx);
            float ssum = 0.0f;
            for (int j = l4 * 16; j < l4 * 16 + 16; ++j) {
                float p = expf(Ss[row][j] - mnew);
                Ss[row][j] = p;
                ssum += p;
            }
            ssum += __shfl_xor(ssum, 1, 4);
            ssum += __shfl_xor(ssum, 2, 4);
            if (l4 == 0) {
                float al = expf(mold - mnew);
                arow[row] = al;
                lrow[row] = lrow[row] * al + ssum;
                mrow[row] = mnew;
            }
        }
        __syncthreads();

        // phase 3: acc = acc*alpha + P·V   (4 rows x 8 cols per thread)
        {
#pragma unroll
            for (int ii = 0; ii < 4; ++ii) {
                float al = arow[ty * 4 + ii];
#pragma unroll
                for (int dd = 0; dd < 8; ++dd) acc[ii][dd] *= al;
            }
#pragma unroll 4
            for (int j = 0; j < BK; ++j) {
                float4 v0 = *(const float4*)&Vs[j][tx * 8];
                float4 v1 = *(const float4*)&Vs[j][tx * 8 + 4];
#pragma unroll
                for (int ii = 0; ii < 4; ++ii) {
                    float p = Ss[ty * 4 + ii][j];
                    acc[ii][0] += p * v0.x; acc[ii][1] += p * v0.y;
                    acc[ii][2] += p * v0.z; acc[ii][3] += p * v0.w;
                    acc[ii][4] += p * v1.x; acc[ii][5] += p * v1.y;
                    acc[ii][6] += p * v1.z; acc[ii][7] += p * v1.w;
                }
            }
        }
    }
    __syncthreads();
#pragma unroll
    for (int ii = 0; ii < 4; ++ii) {
        int i = ty * 4 + ii;
        float inv = 1.0f / lrow[i];
        float4 o0, o1;
        o0.x = acc[ii][0] * inv; o0.y = acc[ii][1] * inv;
        o0.z = acc[ii][2] * inv; o0.w = acc[ii][3] * inv;
        o1.x = acc[ii][4] * inv; o1.y = acc[ii][5] * inv;
        o1.z = acc[ii][6] * inv; o1.w = acc[ii][7] * inv;
        size_t base = (size_t)(n0 + i) * DMODEL + h * HDIM + tx * 8;
        *(float4*)&attn_out[base]     = o0;
        *(float4*)&attn_out[base + 4] = o1;
    }
}

// ---------------------------------------------------------------- LN + gated residual
__global__ __launch_bounds__(256) void final_kernel(const float* __restrict__ o,
                                                    const float* __restrict__ vh,
                                                    const float* __restrict__ lnw,
                                                    const float* __restrict__ lnb,
                                                    const float* __restrict__ gparam,
                                                    float* __restrict__ out) {
    int n = blockIdx.x, t = threadIdx.x;
    size_t base = (size_t)n * DMODEL;
    float x0 = o[base + t], x1 = o[base + t + 256];
    __shared__ float red[4];
    float v = x0 + x1;
#pragma unroll
    for (int off = 32; off > 0; off >>= 1) v += __shfl_down(v, off, 64);
    if ((t & 63) == 0) red[t >> 6] = v;
    __syncthreads();
    float mu = (red[0] + red[1] + red[2] + red[3]) * (1.0f / 512.0f);
    __syncthreads();
    float d0 = x0 - mu, d1 = x1 - mu;
    v = d0 * d0 + d1 * d1;
#pragma unroll
    for (int off = 32; off > 0; off >>= 1) v += __shfl_down(v, off, 64);
    if ((t & 63) == 0) red[t >> 6] = v;
    __syncthreads();
    float var  = (red[0] + red[1] + red[2] + red[3]) * (1.0f / 512.0f);
    float rstd = rsqrtf(var + 1e-5f);
    float gamma = log1pf(expf(gparam[0]));   // softplus
    out[base + t]       = vh[base + t]       + gamma * (d0 * rstd * lnw[t]       + lnb[t]);
    out[base + t + 256] = vh[base + t + 256] + gamma * (d1 * rstd * lnw[t + 256] + lnb[t + 256]);
}

// ---------------------------------------------------------------- launch
extern "C" void kernel_launch(void* const* d_in, const int* in_sizes, int n_in,
                              void* d_out, int out_size, void* d_ws, size_t ws_size,
                              hipStream_t stream) {
    const float* vision_h  = (const float*)d_in[0];
    const int*   prows     = (const int*)d_in[1];
    const int*   pcols     = (const int*)d_in[2];
    const float* pos_w     = (const float*)d_in[3];
    const float* q_w       = (const float*)d_in[4];
    const float* k_w       = (const float*)d_in[5];
    const float* v_w       = (const float*)d_in[6];
    const float* out_w     = (const float*)d_in[7];
    const float* dist_bias = (const float*)d_in[8];
    const float* gamma_p   = (const float*)d_in[9];
    const float* ln_w      = (const float*)d_in[10];
    const float* ln_b      = (const float*)d_in[11];
    float* out = (float*)d_out;
    float* ws  = (float*)d_ws;

    const size_t SZ = (size_t)N_TOK * DMODEL;  // 2M floats = 8MB
    float* pe     = ws;
    float* hpos   = ws + SZ;
    float* Qb     = ws + 2 * SZ;
    float* Kb     = ws + 3 * SZ;
    float* Vb     = ws + 4 * SZ;
    float* attn_o = pe;    // reuse (pe dead after h_pos)
    float* ob     = hpos;  // reuse (hpos dead after Q,K)

    pe_kernel<<<N_TOK, 256, 0, stream>>>(prows, pcols, pe);
    gemm_aw<true ><<<dim3(64, 8), 256, 0, stream>>>(pe, pos_w, vision_h, hpos);
    gemm_aw<false><<<dim3(64, 8), 256, 0, stream>>>(hpos, q_w, nullptr, Qb);
    gemm_aw<false><<<dim3(64, 8), 256, 0, stream>>>(hpos, k_w, nullptr, Kb);
    gemm_aw<false><<<dim3(64, 8), 256, 0, stream>>>(vision_h, v_w, nullptr, Vb);
    attn_kernel<<<dim3(N_TOK / BQ, NHEAD), 256, 0, stream>>>(Qb, Kb, Vb, prows, pcols, dist_bias, attn_o);
    gemm_aw<false><<<dim3(64, 8), 256, 0, stream>>>(attn_o, out_w, nullptr, ob);
    final_kernel<<<N_TOK, 256, 0, stream>>>(ob, vision_h, ln_w, ln_b, gamma_p, out);
}

// Round 2
// 578.023 us; speedup vs baseline: 3.0508x; 3.0508x over previous
//
#include <hip/hip_runtime.h>
#include <math.h>

#define N_TOK 4096
#define DMODEL 512
#define NHEAD 4
#define HDIM 128
#define NBINS 32
#define BQ 64
#define BK 64

typedef __attribute__((ext_vector_type(8))) short bf16x8;
typedef __attribute__((ext_vector_type(4))) float f32x4;
typedef __attribute__((ext_vector_type(8))) unsigned short u16x8;

__device__ __forceinline__ unsigned short f2bf(float x) {
    unsigned int u = __float_as_uint(x);
    u += 0x7FFFu + ((u >> 16) & 1u);   // round-to-nearest-even
    return (unsigned short)(u >> 16);
}

// ---------------------------------------------------------------- PE kernel
__global__ __launch_bounds__(256) void pe_kernel(const int* __restrict__ rows,
                                                 const int* __restrict__ cols,
                                                 float* __restrict__ pe) {
    int n = blockIdx.x, t = threadIdx.x;
    float pos = (float)((t < 128) ? rows[n] : cols[n]);
    int k = t & 127;
    float freq = expf(-0.035977892078032f * (float)(2 * k));
    float ang = pos * freq;
    int base = n * DMODEL + ((t < 128) ? 0 : 256) + 2 * k;
    pe[base]     = sinf(ang);
    pe[base + 1] = cosf(ang);
}

// ---------------------------------------------------------------- GEMM: C = A @ W^T (+ addv)
// TOUT=true writes C transposed: CT[j][n]  (for V so attention gets Vt rows)
template <bool ADD, bool TOUT>
__global__ __launch_bounds__(256) void gemm_aw(const float* __restrict__ A,
                                               const float* __restrict__ W,
                                               const float* __restrict__ addv,
                                               float* __restrict__ C) {
    const int n0 = blockIdx.x * 64;
    const int j0 = blockIdx.y * 64;
    __shared__ float As[64][68];
    __shared__ float Ws[64][68];
    const int t  = threadIdx.x;
    const int tx = t & 15, ty = t >> 4;
    const int lr = t >> 4;
    const int lc = (t & 15) * 4;
    float acc[4][4] = {};

    for (int k0 = 0; k0 < DMODEL; k0 += 64) {
        __syncthreads();
#pragma unroll
        for (int rr = 0; rr < 64; rr += 16) {
            *(float4*)&As[lr + rr][lc] = *(const float4*)&A[(size_t)(n0 + lr + rr) * DMODEL + k0 + lc];
            *(float4*)&Ws[lr + rr][lc] = *(const float4*)&W[(size_t)(j0 + lr + rr) * DMODEL + k0 + lc];
        }
        __syncthreads();
#pragma unroll 4
        for (int kk = 0; kk < 64; kk += 4) {
            float4 a[4], b[4];
#pragma unroll
            for (int ii = 0; ii < 4; ++ii) a[ii] = *(const float4*)&As[ty * 4 + ii][kk];
#pragma unroll
            for (int jj = 0; jj < 4; ++jj) b[jj] = *(const float4*)&Ws[tx * 4 + jj][kk];
#pragma unroll
            for (int ii = 0; ii < 4; ++ii)
#pragma unroll
                for (int jj = 0; jj < 4; ++jj)
                    acc[ii][jj] += a[ii].x * b[jj].x + a[ii].y * b[jj].y +
                                   a[ii].z * b[jj].z + a[ii].w * b[jj].w;
        }
    }
    if (!TOUT) {
#pragma unroll
        for (int ii = 0; ii < 4; ++ii) {
            const int row = n0 + ty * 4 + ii;
            float4 r;
            r.x = acc[ii][0]; r.y = acc[ii][1]; r.z = acc[ii][2]; r.w = acc[ii][3];
            if (ADD) {
                const float4 av = *(const float4*)&addv[(size_t)row * DMODEL + j0 + tx * 4];
                r.x += av.x; r.y += av.y; r.z += av.z; r.w += av.w;
            }
            *(float4*)&C[(size_t)row * DMODEL + j0 + tx * 4] = r;
        }
    } else {
#pragma unroll
        for (int jj = 0; jj < 4; ++jj) {
            float4 r;
            r.x = acc[0][jj]; r.y = acc[1][jj]; r.z = acc[2][jj]; r.w = acc[3][jj];
            *(float4*)&C[(size_t)(j0 + tx * 4 + jj) * N_TOK + n0 + ty * 4] = r;
        }
    }
}

// ---------------------------------------------------------------- MFMA flash attention with distance bias
// grid (N/BQ, H). 256 threads = 4 waves; wave w owns q-rows [w*16, w*16+16).
__global__ __launch_bounds__(256) void attn_mfma(const float* __restrict__ Q,
                                                 const float* __restrict__ K,
                                                 const float* __restrict__ VtG,
                                                 const int* __restrict__ prows,
                                                 const int* __restrict__ pcols,
                                                 const float* __restrict__ dist_bias,
                                                 float* __restrict__ attn_out) {
    const int h  = blockIdx.y;
    const int n0 = blockIdx.x * BQ;
    __shared__ unsigned short Qs[BQ][136];    // +8 pad: 272B stride
    __shared__ unsigned short Ks[BK][136];
    __shared__ unsigned short Vts[HDIM][72];  // Vt[d][kv], +8 pad: 144B stride
    __shared__ unsigned short Ps[BQ][72];
    __shared__ float biasT[3043];

    const int t    = threadIdx.x;
    const int wid  = t >> 6;
    const int lane = t & 63;
    const int lg   = lane >> 4;   // 0..3
    const int li   = lane & 15;   // 0..15
    const int qbase = wid * 16;

    // per-head bias LUT over s = dr^2+dc^2
    for (int idx = t; idx < 3043; idx += 256) {
        float d  = sqrtf((float)idx);
        int bin  = (int)(log1pf(d) * (31.0f / 4.0529789877f));
        bin = bin > 31 ? 31 : bin;
        biasT[idx] = dist_bias[h * NBINS + bin];
    }
    // stage Q (64x128 f32 -> bf16)
    for (int idx = t; idx < BQ * 16; idx += 256) {
        int row = idx >> 4, ch = idx & 15;
        const float* src = &Q[(size_t)(n0 + row) * DMODEL + h * HDIM + ch * 8];
        float4 a = *(const float4*)src, b = *(const float4*)(src + 4);
        u16x8 w;
        w[0]=f2bf(a.x); w[1]=f2bf(a.y); w[2]=f2bf(a.z); w[3]=f2bf(a.w);
        w[4]=f2bf(b.x); w[5]=f2bf(b.y); w[6]=f2bf(b.z); w[7]=f2bf(b.w);
        *(u16x8*)&Qs[row][ch * 8] = w;
    }
    __syncthreads();

    // persistent Q A-fragments: lane holds Q[qbase+li][kc*32 + lg*8 + 0..7]
    bf16x8 qf[4];
#pragma unroll
    for (int kc = 0; kc < 4; ++kc)
        qf[kc] = *(const bf16x8*)&Qs[qbase + li][kc * 32 + lg * 8];

    // q coords for the 4 C-layout rows this lane owns: row = qbase + lg*4 + r
    int qr_[4], qc_[4];
#pragma unroll
    for (int r = 0; r < 4; ++r) {
        qr_[r] = prows[n0 + qbase + lg * 4 + r];
        qc_[r] = pcols[n0 + qbase + lg * 4 + r];
    }
    float m_[4] = {-1e30f, -1e30f, -1e30f, -1e30f};
    float l_[4] = {0.f, 0.f, 0.f, 0.f};
    f32x4 accO[8];
#pragma unroll
    for (int dt = 0; dt < 8; ++dt) accO[dt] = (f32x4){0.f, 0.f, 0.f, 0.f};

    for (int kb = 0; kb < N_TOK / BK; ++kb) {
        const int m0 = kb * BK;
        __syncthreads();   // all waves done reading previous K/Vt
        for (int idx = t; idx < BK * 16; idx += 256) {
            int row = idx >> 4, ch = idx & 15;
            const float* src = &K[(size_t)(m0 + row) * DMODEL + h * HDIM + ch * 8];
            float4 a = *(const float4*)src, b = *(const float4*)(src + 4);
            u16x8 w;
            w[0]=f2bf(a.x); w[1]=f2bf(a.y); w[2]=f2bf(a.z); w[3]=f2bf(a.w);
            w[4]=f2bf(b.x); w[5]=f2bf(b.y); w[6]=f2bf(b.z); w[7]=f2bf(b.w);
            *(u16x8*)&Ks[row][ch * 8] = w;
        }
        for (int idx = t; idx < HDIM * 8; idx += 256) {
            int row = idx >> 3, ch = idx & 7;
            const float* src = &VtG[(size_t)(h * HDIM + row) * N_TOK + m0 + ch * 8];
            float4 a = *(const float4*)src, b = *(const float4*)(src + 4);
            u16x8 w;
            w[0]=f2bf(a.x); w[1]=f2bf(a.y); w[2]=f2bf(a.z); w[3]=f2bf(a.w);
            w[4]=f2bf(b.x); w[5]=f2bf(b.y); w[6]=f2bf(b.z); w[7]=f2bf(b.w);
            *(u16x8*)&Vts[row][ch * 8] = w;
        }
        __syncthreads();

        // ---- S = Q K^T : wave computes 16(q) x 64(k), 4 j-tiles x 4 k-chunks
        f32x4 s[4];
#pragma unroll
        for (int jt = 0; jt < 4; ++jt) {
            f32x4 acc = {0.f, 0.f, 0.f, 0.f};
#pragma unroll
            for (int kc = 0; kc < 4; ++kc) {
                bf16x8 kf = *(const bf16x8*)&Ks[jt * 16 + li][kc * 32 + lg * 8];
                acc = __builtin_amdgcn_mfma_f32_16x16x32_bf16(qf[kc], kf, acc, 0, 0, 0);
            }
            s[jt] = acc;
        }

        // ---- scale + distance bias (C layout: row = qbase+lg*4+r, col = jt*16+li)
        float p[4][4];
#pragma unroll
        for (int jt = 0; jt < 4; ++jt) {
            int krj = prows[m0 + jt * 16 + li];
            int kcj = pcols[m0 + jt * 16 + li];
#pragma unroll
            for (int r = 0; r < 4; ++r) {
                int dr = qr_[r] - krj, dc = qc_[r] - kcj;
                p[jt][r] = s[jt][r] * 0.08838834764831845f + biasT[dr * dr + dc * dc];
            }
        }

        // ---- online softmax per row (reduce over jt regs + 16-lane group)
#pragma unroll
        for (int r = 0; r < 4; ++r) {
            float mx = fmaxf(fmaxf(p[0][r], p[1][r]), fmaxf(p[2][r], p[3][r]));
            mx = fmaxf(mx, __shfl_xor(mx, 1));
            mx = fmaxf(mx, __shfl_xor(mx, 2));
            mx = fmaxf(mx, __shfl_xor(mx, 4));
            mx = fmaxf(mx, __shfl_xor(mx, 8));
            float mnew  = fmaxf(m_[r], mx);
            float alpha = __expf(m_[r] - mnew);
            float rs = 0.f;
#pragma unroll
            for (int jt = 0; jt < 4; ++jt) { p[jt][r] = __expf(p[jt][r] - mnew); rs += p[jt][r]; }
            rs += __shfl_xor(rs, 1);
            rs += __shfl_xor(rs, 2);
            rs += __shfl_xor(rs, 4);
            rs += __shfl_xor(rs, 8);
            l_[r] = l_[r] * alpha + rs;
            m_[r] = mnew;
#pragma unroll
            for (int dt = 0; dt < 8; ++dt) accO[dt][r] *= alpha;
        }

        // ---- P -> LDS (bf16), wave-private rows; compiler orders the LDS ops
#pragma unroll
        for (int r = 0; r < 4; ++r)
#pragma unroll
            for (int jt = 0; jt < 4; ++jt)
                Ps[qbase + lg * 4 + r][jt * 16 + li] = f2bf(p[jt][r]);

        // ---- O += P V : A-frag = P[qbase+li][k], B-frag = Vt[d][k]
        bf16x8 pf0 = *(const bf16x8*)&Ps[qbase + li][lg * 8];
        bf16x8 pf1 = *(const bf16x8*)&Ps[qbase + li][32 + lg * 8];
#pragma unroll
        for (int dt = 0; dt < 8; ++dt) {
            bf16x8 vf0 = *(const bf16x8*)&Vts[dt * 16 + li][lg * 8];
            bf16x8 vf1 = *(const bf16x8*)&Vts[dt * 16 + li][32 + lg * 8];
            accO[dt] = __builtin_amdgcn_mfma_f32_16x16x32_bf16(pf0, vf0, accO[dt], 0, 0, 0);
            accO[dt] = __builtin_amdgcn_mfma_f32_16x16x32_bf16(pf1, vf1, accO[dt], 0, 0, 0);
        }
    }

    // ---- epilogue: normalize, store fp32
#pragma unroll
    for (int r = 0; r < 4; ++r) {
        float inv = 1.0f / l_[r];
        int row = n0 + qbase + lg * 4 + r;
#pragma unroll
        for (int dt = 0; dt < 8; ++dt)
            attn_out[(size_t)row * DMODEL + h * HDIM + dt * 16 + li] = accO[dt][r] * inv;
    }
}

// ---------------------------------------------------------------- LN + gated residual
__global__ __launch_bounds__(256) void final_kernel(const float* __restrict__ o,
                                                    const float* __restrict__ vh,
                                                    const float* __restrict__ lnw,
                                                    const float* __restrict__ lnb,
                                                    const float* __restrict__ gparam,
                                                    float* __restrict__ out) {
    int n = blockIdx.x, t = threadIdx.x;
    size_t base = (size_t)n * DMODEL;
    float x0 = o[base + t], x1 = o[base + t + 256];
    __shared__ float red[4];
    float v = x0 + x1;
#pragma unroll
    for (int off = 32; off > 0; off >>= 1) v += __shfl_down(v, off, 64);
    if ((t & 63) == 0) red[t >> 6] = v;
    __syncthreads();
    float mu = (red[0] + red[1] + red[2] + red[3]) * (1.0f / 512.0f);
    __syncthreads();
    float d0 = x0 - mu, d1 = x1 - mu;
    v = d0 * d0 + d1 * d1;
#pragma unroll
    for (int off = 32; off > 0; off >>= 1) v += __shfl_down(v, off, 64);
    if ((t & 63) == 0) red[t >> 6] = v;
    __syncthreads();
    float var  = (red[0] + red[1] + red[2] + red[3]) * (1.0f / 512.0f);
    float rstd = rsqrtf(var + 1e-5f);
    float gamma = log1pf(expf(gparam[0]));
    out[base + t]       = vh[base + t]       + gamma * (d0 * rstd * lnw[t]       + lnb[t]);
    out[base + t + 256] = vh[base + t + 256] + gamma * (d1 * rstd * lnw[t + 256] + lnb[t + 256]);
}

// ---------------------------------------------------------------- launch
extern "C" void kernel_launch(void* const* d_in, const int* in_sizes, int n_in,
                              void* d_out, int out_size, void* d_ws, size_t ws_size,
                              hipStream_t stream) {
    const float* vision_h  = (const float*)d_in[0];
    const int*   prows     = (const int*)d_in[1];
    const int*   pcols     = (const int*)d_in[2];
    const float* pos_w     = (const float*)d_in[3];
    const float* q_w       = (const float*)d_in[4];
    const float* k_w       = (const float*)d_in[5];
    const float* v_w       = (const float*)d_in[6];
    const float* out_w     = (const float*)d_in[7];
    const float* dist_bias = (const float*)d_in[8];
    const float* gamma_p   = (const float*)d_in[9];
    const float* ln_w      = (const float*)d_in[10];
    const float* ln_b      = (const float*)d_in[11];
    float* out = (float*)d_out;
    float* ws  = (float*)d_ws;

    const size_t SZ = (size_t)N_TOK * DMODEL;  // 2M floats = 8MB
    float* pe     = ws;
    float* hpos   = ws + SZ;
    float* Qb     = ws + 2 * SZ;
    float* Kb     = ws + 3 * SZ;
    float* Vtb    = ws + 4 * SZ;   // transposed V: [512][4096]
    float* attn_o = pe;            // reuse
    float* ob     = hpos;          // reuse

    pe_kernel<<<N_TOK, 256, 0, stream>>>(prows, pcols, pe);
    gemm_aw<true,  false><<<dim3(64, 8), 256, 0, stream>>>(pe, pos_w, vision_h, hpos);
    gemm_aw<false, false><<<dim3(64, 8), 256, 0, stream>>>(hpos, q_w, nullptr, Qb);
    gemm_aw<false, false><<<dim3(64, 8), 256, 0, stream>>>(hpos, k_w, nullptr, Kb);
    gemm_aw<false, true ><<<dim3(64, 8), 256, 0, stream>>>(vision_h, v_w, nullptr, Vtb);
    attn_mfma<<<dim3(N_TOK / BQ, NHEAD), 256, 0, stream>>>(Qb, Kb, Vtb, prows, pcols, dist_bias, attn_o);
    gemm_aw<false, false><<<dim3(64, 8), 256, 0, stream>>>(attn_o, out_w, nullptr, ob);
    final_kernel<<<N_TOK, 256, 0, stream>>>(ob, vision_h, ln_w, ln_b, gamma_p, out);
}

// Round 4
// 376.899 us; speedup vs baseline: 4.6787x; 1.5336x over previous
//
#include <hip/hip_runtime.h>
#include <math.h>

#define N_TOK 4096
#define DMODEL 512
#define NHEAD 4
#define HDIM 128
#define NBINS 32
#define BQ 64
#define BK 64
#define NSPLIT 2
#define KV_PER_SPLIT (N_TOK / NSPLIT)

typedef __attribute__((ext_vector_type(8))) short bf16x8;
typedef __attribute__((ext_vector_type(4))) float f32x4;
typedef __attribute__((ext_vector_type(8))) unsigned short u16x8;
typedef __attribute__((ext_vector_type(4))) unsigned short u16x4;

__device__ __forceinline__ unsigned short f2bf(float x) {
    unsigned int u = __float_as_uint(x);
    u += 0x7FFFu + ((u >> 16) & 1u);   // round-to-nearest-even
    return (unsigned short)(u >> 16);
}
__device__ __forceinline__ float bf2f(unsigned short u) {
    return __uint_as_float(((unsigned int)u) << 16);
}

// ---------------------------------------------------------------- PE kernel
__global__ __launch_bounds__(256) void pe_kernel(const int* __restrict__ rows,
                                                 const int* __restrict__ cols,
                                                 float* __restrict__ pe) {
    int n = blockIdx.x, t = threadIdx.x;
    float pos = (float)((t < 128) ? rows[n] : cols[n]);
    int k = t & 127;
    float freq = expf(-0.035977892078032f * (float)(2 * k));
    float ang = pos * freq;
    int base = n * DMODEL + ((t < 128) ? 0 : 256) + 2 * k;
    pe[base]     = sinf(ang);
    pe[base + 1] = cosf(ang);
}

// ---------------------------------------------------------------- GEMM: C = A @ W^T
// OUTMODE: 0 = f32, 1 = f32 + addv, 2 = bf16 (scaled), 3 = bf16 transposed CT[j][n]
template <int OUTMODE>
__global__ __launch_bounds__(256) void gemm_aw(const float* __restrict__ A,
                                               const float* __restrict__ W,
                                               const float* __restrict__ addv,
                                               void* __restrict__ Cv,
                                               float scale) {
    const int n0 = blockIdx.x * 64;
    const int j0 = blockIdx.y * 64;
    __shared__ float As[64][68];
    __shared__ float Ws[64][68];
    const int t  = threadIdx.x;
    const int tx = t & 15, ty = t >> 4;
    const int lr = t >> 4;
    const int lc = (t & 15) * 4;
    float acc[4][4] = {};

    for (int k0 = 0; k0 < DMODEL; k0 += 64) {
        __syncthreads();
#pragma unroll
        for (int rr = 0; rr < 64; rr += 16) {
            *(float4*)&As[lr + rr][lc] = *(const float4*)&A[(size_t)(n0 + lr + rr) * DMODEL + k0 + lc];
            *(float4*)&Ws[lr + rr][lc] = *(const float4*)&W[(size_t)(j0 + lr + rr) * DMODEL + k0 + lc];
        }
        __syncthreads();
#pragma unroll 4
        for (int kk = 0; kk < 64; kk += 4) {
            float4 a[4], b[4];
#pragma unroll
            for (int ii = 0; ii < 4; ++ii) a[ii] = *(const float4*)&As[ty * 4 + ii][kk];
#pragma unroll
            for (int jj = 0; jj < 4; ++jj) b[jj] = *(const float4*)&Ws[tx * 4 + jj][kk];
#pragma unroll
            for (int ii = 0; ii < 4; ++ii)
#pragma unroll
                for (int jj = 0; jj < 4; ++jj)
                    acc[ii][jj] += a[ii].x * b[jj].x + a[ii].y * b[jj].y +
                                   a[ii].z * b[jj].z + a[ii].w * b[jj].w;
        }
    }
    if (OUTMODE == 0 || OUTMODE == 1) {
        float* C = (float*)Cv;
#pragma unroll
        for (int ii = 0; ii < 4; ++ii) {
            const int row = n0 + ty * 4 + ii;
            float4 r;
            r.x = acc[ii][0]; r.y = acc[ii][1]; r.z = acc[ii][2]; r.w = acc[ii][3];
            if (OUTMODE == 1) {
                const float4 av = *(const float4*)&addv[(size_t)row * DMODEL + j0 + tx * 4];
                r.x += av.x; r.y += av.y; r.z += av.z; r.w += av.w;
            }
            *(float4*)&C[(size_t)row * DMODEL + j0 + tx * 4] = r;
        }
    } else if (OUTMODE == 2) {
        unsigned short* C = (unsigned short*)Cv;
#pragma unroll
        for (int ii = 0; ii < 4; ++ii) {
            u16x4 r;
#pragma unroll
            for (int jj = 0; jj < 4; ++jj) r[jj] = f2bf(acc[ii][jj] * scale);
            *(u16x4*)&C[(size_t)(n0 + ty * 4 + ii) * DMODEL + j0 + tx * 4] = r;
        }
    } else {
        unsigned short* C = (unsigned short*)Cv;
#pragma unroll
        for (int jj = 0; jj < 4; ++jj) {
            u16x4 r;
#pragma unroll
            for (int ii = 0; ii < 4; ++ii) r[ii] = f2bf(acc[ii][jj]);
            *(u16x4*)&C[(size_t)(j0 + tx * 4 + jj) * N_TOK + n0 + ty * 4] = r;
        }
    }
}

// ---------------------------------------------------------------- MFMA flash attention, K-split
// grid (N/BQ, H, NSPLIT). 256 threads = 4 waves; wave w owns q-rows [w*16, w*16+16).
__global__ __launch_bounds__(256) void attn_mfma(const unsigned short* __restrict__ Qb,
                                                 const unsigned short* __restrict__ Kb,
                                                 const unsigned short* __restrict__ Vtb,
                                                 const int* __restrict__ prows,
                                                 const int* __restrict__ pcols,
                                                 const float* __restrict__ dist_bias,
                                                 unsigned short* __restrict__ Opart,
                                                 float* __restrict__ Mp,
                                                 float* __restrict__ Lp) {
    const int h  = blockIdx.y;
    const int n0 = blockIdx.x * BQ;
    const int sp = blockIdx.z;
    __shared__ unsigned short Ks[BK][136];    // +8 pad
    __shared__ unsigned short Vts[HDIM][72];  // Vt[d][kv], +8 pad
    __shared__ unsigned short Ps[BQ][72];
    __shared__ float biasT[3043];
    __shared__ int krs[BK], kcs[BK];

    const int t    = threadIdx.x;
    const int lane = t & 63;
    const int lg   = lane >> 4;
    const int li   = lane & 15;
    const int qbase = (t >> 6) * 16;

    for (int idx = t; idx < 3043; idx += 256) {
        float d  = sqrtf((float)idx);
        int bin  = (int)(log1pf(d) * (31.0f / 4.0529789877f));
        bin = bin > 31 ? 31 : bin;
        biasT[idx] = dist_bias[h * NBINS + bin];
    }

    // persistent Q A-fragments direct from global bf16 (scale pre-folded)
    bf16x8 qf[4];
    {
        const unsigned short* qptr = &Qb[(size_t)(n0 + qbase + li) * DMODEL + h * HDIM];
#pragma unroll
        for (int kc = 0; kc < 4; ++kc)
            qf[kc] = *(const bf16x8*)&qptr[kc * 32 + lg * 8];
    }
    int qr_[4], qc_[4];
#pragma unroll
    for (int r = 0; r < 4; ++r) {
        qr_[r] = prows[n0 + qbase + lg * 4 + r];
        qc_[r] = pcols[n0 + qbase + lg * 4 + r];
    }
    float m_[4] = {-1e30f, -1e30f, -1e30f, -1e30f};
    float l_[4] = {0.f, 0.f, 0.f, 0.f};
    f32x4 accO[8];
#pragma unroll
    for (int dt = 0; dt < 8; ++dt) accO[dt] = (f32x4){0.f, 0.f, 0.f, 0.f};

    // staging registers (T14 async split: load early, ds_write late)
    // K: kreg[i] <-> Ks[(t>>4)+i*16][(t&15)*8 .. +8)   (full 64x128 coverage)
    // V: vreg[i] <-> Vts[(t>>3)+i*32][(t&7)*8 .. +8)   (full 128x64 coverage)
    u16x8 kreg[4], vreg[4];
    int krreg = 0, kcreg = 0;
    const int ktr = t >> 4, kch = (t & 15) * 8;
    const int vtr = t >> 3, vch = (t & 7) * 8;

    int m0 = sp * KV_PER_SPLIT;
    {   // prefetch tile 0
#pragma unroll
        for (int i = 0; i < 4; ++i)
            kreg[i] = *(const u16x8*)&Kb[(size_t)(m0 + ktr + i * 16) * DMODEL + h * HDIM + kch];
#pragma unroll
        for (int i = 0; i < 4; ++i)
            vreg[i] = *(const u16x8*)&Vtb[(size_t)(h * HDIM + vtr + i * 32) * N_TOK + m0 + vch];
        if (t < BK) { krreg = prows[m0 + t]; kcreg = pcols[m0 + t]; }
    }

    for (int kb = 0; kb < KV_PER_SPLIT / BK; ++kb, m0 += BK) {
        __syncthreads();   // all waves done reading previous K/Vt
#pragma unroll
        for (int i = 0; i < 4; ++i) *(u16x8*)&Ks[ktr + i * 16][kch] = kreg[i];
#pragma unroll
        for (int i = 0; i < 4; ++i) *(u16x8*)&Vts[vtr + i * 32][vch] = vreg[i];
        if (t < BK) { krs[t] = krreg; kcs[t] = kcreg; }
        __syncthreads();

        if (kb + 1 < KV_PER_SPLIT / BK) {   // issue next tile's loads early
            const int m1 = m0 + BK;
#pragma unroll
            for (int i = 0; i < 4; ++i)
                kreg[i] = *(const u16x8*)&Kb[(size_t)(m1 + ktr + i * 16) * DMODEL + h * HDIM + kch];
#pragma unroll
            for (int i = 0; i < 4; ++i)
                vreg[i] = *(const u16x8*)&Vtb[(size_t)(h * HDIM + vtr + i * 32) * N_TOK + m1 + vch];
            if (t < BK) { krreg = prows[m1 + t]; kcreg = pcols[m1 + t]; }
        }

        // ---- S = Q K^T
        f32x4 s[4];
        __builtin_amdgcn_s_setprio(1);
#pragma unroll
        for (int jt = 0; jt < 4; ++jt) {
            f32x4 acc = {0.f, 0.f, 0.f, 0.f};
#pragma unroll
            for (int kc = 0; kc < 4; ++kc) {
                bf16x8 kf = *(const bf16x8*)&Ks[jt * 16 + li][kc * 32 + lg * 8];
                acc = __builtin_amdgcn_mfma_f32_16x16x32_bf16(qf[kc], kf, acc, 0, 0, 0);
            }
            s[jt] = acc;
        }
        __builtin_amdgcn_s_setprio(0);

        // ---- bias (scale folded into Q already)
        float p[4][4];
#pragma unroll
        for (int jt = 0; jt < 4; ++jt) {
            int krj = krs[jt * 16 + li], kcj = kcs[jt * 16 + li];
#pragma unroll
            for (int r = 0; r < 4; ++r) {
                int dr = qr_[r] - krj, dc = qc_[r] - kcj;
                p[jt][r] = s[jt][r] + biasT[dr * dr + dc * dc];
            }
        }

        // ---- online softmax per row
#pragma unroll
        for (int r = 0; r < 4; ++r) {
            float mx = fmaxf(fmaxf(p[0][r], p[1][r]), fmaxf(p[2][r], p[3][r]));
            mx = fmaxf(mx, __shfl_xor(mx, 1));
            mx = fmaxf(mx, __shfl_xor(mx, 2));
            mx = fmaxf(mx, __shfl_xor(mx, 4));
            mx = fmaxf(mx, __shfl_xor(mx, 8));
            float mnew  = fmaxf(m_[r], mx);
            float alpha = __expf(m_[r] - mnew);
            float rs = 0.f;
#pragma unroll
            for (int jt = 0; jt < 4; ++jt) { p[jt][r] = __expf(p[jt][r] - mnew); rs += p[jt][r]; }
            rs += __shfl_xor(rs, 1);
            rs += __shfl_xor(rs, 2);
            rs += __shfl_xor(rs, 4);
            rs += __shfl_xor(rs, 8);
            l_[r] = l_[r] * alpha + rs;
            m_[r] = mnew;
#pragma unroll
            for (int dt = 0; dt < 8; ++dt) accO[dt][r] *= alpha;
        }

        // ---- P -> LDS bf16 (wave-private rows)
#pragma unroll
        for (int r = 0; r < 4; ++r)
#pragma unroll
            for (int jt = 0; jt < 4; ++jt)
                Ps[qbase + lg * 4 + r][jt * 16 + li] = f2bf(p[jt][r]);

        // ---- O += P V
        bf16x8 pf0 = *(const bf16x8*)&Ps[qbase + li][lg * 8];
        bf16x8 pf1 = *(const bf16x8*)&Ps[qbase + li][32 + lg * 8];
        __builtin_amdgcn_s_setprio(1);
#pragma unroll
        for (int dt = 0; dt < 8; ++dt) {
            bf16x8 vf0 = *(const bf16x8*)&Vts[dt * 16 + li][lg * 8];
            bf16x8 vf1 = *(const bf16x8*)&Vts[dt * 16 + li][32 + lg * 8];
            accO[dt] = __builtin_amdgcn_mfma_f32_16x16x32_bf16(pf0, vf0, accO[dt], 0, 0, 0);
            accO[dt] = __builtin_amdgcn_mfma_f32_16x16x32_bf16(pf1, vf1, accO[dt], 0, 0, 0);
        }
        __builtin_amdgcn_s_setprio(0);
    }

    // ---- epilogue: normalize, store bf16 partial O + (m,l)
#pragma unroll
    for (int r = 0; r < 4; ++r) {
        float inv = 1.0f / l_[r];
        int row = n0 + qbase + lg * 4 + r;
#pragma unroll
        for (int dt = 0; dt < 8; ++dt)
            Opart[(size_t)sp * N_TOK * DMODEL + (size_t)row * DMODEL + h * HDIM + dt * 16 + li] =
                f2bf(accO[dt][r] * inv);
        if (li == 0) {
            Mp[((size_t)sp * NHEAD + h) * N_TOK + row] = m_[r];
            Lp[((size_t)sp * NHEAD + h) * N_TOK + row] = l_[r];
        }
    }
}

// ---------------------------------------------------------------- combine K-split partials
__global__ __launch_bounds__(256) void combine_kernel(const unsigned short* __restrict__ Opart,
                                                      const float* __restrict__ Mp,
                                                      const float* __restrict__ Lp,
                                                      float* __restrict__ out) {
    int n = blockIdx.x, t = threadIdx.x;
#pragma unroll
    for (int d0 = t; d0 < DMODEL; d0 += 256) {
        int h = d0 >> 7;
        float m1 = Mp[(size_t)h * N_TOK + n];
        float m2 = Mp[((size_t)NHEAD + h) * N_TOK + n];
        float l1 = Lp[(size_t)h * N_TOK + n];
        float l2 = Lp[((size_t)NHEAD + h) * N_TOK + n];
        float m  = fmaxf(m1, m2);
        float a1 = __expf(m1 - m) * l1, a2 = __expf(m2 - m) * l2;
        float inv = 1.0f / (a1 + a2);
        float o1 = bf2f(Opart[(size_t)n * DMODEL + d0]);
        float o2 = bf2f(Opart[(size_t)N_TOK * DMODEL + (size_t)n * DMODEL + d0]);
        out[(size_t)n * DMODEL + d0] = (a1 * o1 + a2 * o2) * inv;
    }
}

// ---------------------------------------------------------------- LN + gated residual
__global__ __launch_bounds__(256) void final_kernel(const float* __restrict__ o,
                                                    const float* __restrict__ vh,
                                                    const float* __restrict__ lnw,
                                                    const float* __restrict__ lnb,
                                                    const float* __restrict__ gparam,
                                                    float* __restrict__ out) {
    int n = blockIdx.x, t = threadIdx.x;
    size_t base = (size_t)n * DMODEL;
    float x0 = o[base + t], x1 = o[base + t + 256];
    __shared__ float red[4];
    float v = x0 + x1;
#pragma unroll
    for (int off = 32; off > 0; off >>= 1) v += __shfl_down(v, off, 64);
    if ((t & 63) == 0) red[t >> 6] = v;
    __syncthreads();
    float mu = (red[0] + red[1] + red[2] + red[3]) * (1.0f / 512.0f);
    __syncthreads();
    float d0 = x0 - mu, d1 = x1 - mu;
    v = d0 * d0 + d1 * d1;
#pragma unroll
    for (int off = 32; off > 0; off >>= 1) v += __shfl_down(v, off, 64);
    if ((t & 63) == 0) red[t >> 6] = v;
    __syncthreads();
    float var  = (red[0] + red[1] + red[2] + red[3]) * (1.0f / 512.0f);
    float rstd = rsqrtf(var + 1e-5f);
    float gamma = log1pf(expf(gparam[0]));
    out[base + t]       = vh[base + t]       + gamma * (d0 * rstd * lnw[t]       + lnb[t]);
    out[base + t + 256] = vh[base + t + 256] + gamma * (d1 * rstd * lnw[t + 256] + lnb[t + 256]);
}

// ---------------------------------------------------------------- launch
extern "C" void kernel_launch(void* const* d_in, const int* in_sizes, int n_in,
                              void* d_out, int out_size, void* d_ws, size_t ws_size,
                              hipStream_t stream) {
    const float* vision_h  = (const float*)d_in[0];
    const int*   prows     = (const int*)d_in[1];
    const int*   pcols     = (const int*)d_in[2];
    const float* pos_w     = (const float*)d_in[3];
    const float* q_w       = (const float*)d_in[4];
    const float* k_w       = (const float*)d_in[5];
    const float* v_w       = (const float*)d_in[6];
    const float* out_w     = (const float*)d_in[7];
    const float* dist_bias = (const float*)d_in[8];
    const float* gamma_p   = (const float*)d_in[9];
    const float* ln_w      = (const float*)d_in[10];
    const float* ln_b      = (const float*)d_in[11];
    float* out = (float*)d_out;
    char* base = (char*)d_ws;

    const size_t MB = 1024 * 1024;
    float*          pe_f   = (float*)(base + 0);            // 8 MB
    float*          hpos_f = (float*)(base + 8 * MB);       // 8 MB
    unsigned short* Qb     = (unsigned short*)(base + 16 * MB);  // 4 MB
    unsigned short* Kb     = (unsigned short*)(base + 20 * MB);  // 4 MB
    unsigned short* Vtb    = (unsigned short*)(base + 24 * MB);  // 4 MB
    unsigned short* Opart  = (unsigned short*)(base + 28 * MB);  // 2 x 4 MB
    float*          Mp     = (float*)(base + 36 * MB);      // 128 KB
    float*          Lp     = (float*)(base + 36 * MB + 131072);
    float*          attn_o = pe_f;    // reuse
    float*          ob     = hpos_f;  // reuse

    const float qscale = 0.08838834764831845f;  // 1/sqrt(128)

    pe_kernel<<<N_TOK, 256, 0, stream>>>(prows, pcols, pe_f);
    gemm_aw<1><<<dim3(64, 8), 256, 0, stream>>>(pe_f, pos_w, vision_h, hpos_f, 1.0f);
    gemm_aw<2><<<dim3(64, 8), 256, 0, stream>>>(hpos_f, q_w, nullptr, Qb, qscale);
    gemm_aw<2><<<dim3(64, 8), 256, 0, stream>>>(hpos_f, k_w, nullptr, Kb, 1.0f);
    gemm_aw<3><<<dim3(64, 8), 256, 0, stream>>>(vision_h, v_w, nullptr, Vtb, 1.0f);
    attn_mfma<<<dim3(N_TOK / BQ, NHEAD, NSPLIT), 256, 0, stream>>>(Qb, Kb, Vtb, prows, pcols,
                                                                   dist_bias, Opart, Mp, Lp);
    combine_kernel<<<N_TOK, 256, 0, stream>>>(Opart, Mp, Lp, attn_o);
    gemm_aw<0><<<dim3(64, 8), 256, 0, stream>>>(attn_o, out_w, nullptr, ob, 1.0f);
    final_kernel<<<N_TOK, 256, 0, stream>>>(ob, vision_h, ln_w, ln_b, gamma_p, out);
}

// Round 5
// 188.305 us; speedup vs baseline: 9.3646x; 2.0015x over previous
//
#include <hip/hip_runtime.h>
#include <math.h>

#define N_TOK 4096
#define DMODEL 512
#define NHEAD 4
#define HDIM 128
#define NBINS 32
#define BQ 64
#define BK 64
#define NSPLIT 2
#define KV_PER_SPLIT (N_TOK / NSPLIT)

typedef __attribute__((ext_vector_type(8))) short bf16x8;
typedef __attribute__((ext_vector_type(4))) float f32x4;
typedef __attribute__((ext_vector_type(8))) unsigned short u16x8;
typedef __attribute__((ext_vector_type(4))) unsigned short u16x4;

__device__ __forceinline__ unsigned short f2bf(float x) {
    unsigned int u = __float_as_uint(x);
    u += 0x7FFFu + ((u >> 16) & 1u);   // round-to-nearest-even
    return (unsigned short)(u >> 16);
}
__device__ __forceinline__ float bf2f(unsigned short u) {
    return __uint_as_float(((unsigned int)u) << 16);
}

// ---------------------------------------------------------------- PE + vision_h -> bf16
__global__ __launch_bounds__(256) void pe_prep(const int* __restrict__ rows,
                                               const int* __restrict__ cols,
                                               const float* __restrict__ vh,
                                               unsigned short* __restrict__ pe_bf,
                                               unsigned short* __restrict__ vh_bf) {
    int n = blockIdx.x, t = threadIdx.x;
    float pos = (float)((t < 128) ? rows[n] : cols[n]);
    int k = t & 127;
    float freq = expf(-0.035977892078032f * (float)(2 * k));
    float ang = pos * freq;
    int base = n * DMODEL + ((t < 128) ? 0 : 256) + 2 * k;
    pe_bf[base]     = f2bf(sinf(ang));
    pe_bf[base + 1] = f2bf(cosf(ang));
    float2 v = *(const float2*)&vh[(size_t)n * DMODEL + t * 2];
    vh_bf[(size_t)n * DMODEL + t * 2]     = f2bf(v.x);
    vh_bf[(size_t)n * DMODEL + t * 2 + 1] = f2bf(v.y);
}

// ---------------------------------------------------------------- 5 weights fp32 -> bf16
__global__ __launch_bounds__(256) void wconv5(const float* __restrict__ w0, const float* __restrict__ w1,
                                              const float* __restrict__ w2, const float* __restrict__ w3,
                                              const float* __restrict__ w4,
                                              unsigned short* __restrict__ dstbase) {
    const float* srcs[5] = {w0, w1, w2, w3, w4};
    const float* src = srcs[blockIdx.y];
    unsigned short* dst = dstbase + (size_t)blockIdx.y * DMODEL * DMODEL;
    int idx = (blockIdx.x * 256 + threadIdx.x) * 4;
    float4 v = *(const float4*)&src[idx];
    u16x4 r;
    r[0] = f2bf(v.x); r[1] = f2bf(v.y); r[2] = f2bf(v.z); r[3] = f2bf(v.w);
    *(u16x4*)&dst[idx] = r;
}

// ---------------------------------------------------------------- MFMA GEMM: C[M][N] = A[M][K] @ B[N][K]^T
// A, B bf16; 128x128 tile, BK=64, 4 waves 2x2, wave tile 64x64 (4x4 fragments).
template <bool ADD, bool BF16OUT>
__global__ __launch_bounds__(256) void gemm_mfma(const unsigned short* __restrict__ A,
                                                 const unsigned short* __restrict__ B,
                                                 const float* __restrict__ addv,
                                                 void* __restrict__ Cv,
                                                 int M, int N, int K, float scale) {
    const int n0 = blockIdx.x * 128;   // M-tile
    const int j0 = blockIdx.y * 128;   // N-tile
    __shared__ unsigned short As[128][72];   // +8 pad
    __shared__ unsigned short Bs[128][72];
    const int t    = threadIdx.x;
    const int wid  = t >> 6;
    const int wr   = wid >> 1, wc = wid & 1;
    const int lane = t & 63;
    const int lg   = lane >> 4, li = lane & 15;

    // staging: thread covers rows (t>>3)+i*32, cols (t&7)*8..+8  (full 128x64)
    const int str = t >> 3;
    const int sc  = (t & 7) * 8;

    f32x4 acc[4][4];
#pragma unroll
    for (int i = 0; i < 4; ++i)
#pragma unroll
        for (int j = 0; j < 4; ++j) acc[i][j] = (f32x4){0.f, 0.f, 0.f, 0.f};

    u16x8 areg[4], breg[4];
#pragma unroll
    for (int i = 0; i < 4; ++i) {
        areg[i] = *(const u16x8*)&A[(size_t)(n0 + str + i * 32) * K + sc];
        breg[i] = *(const u16x8*)&B[(size_t)(j0 + str + i * 32) * K + sc];
    }
    for (int k0 = 0; k0 < K; k0 += 64) {
        __syncthreads();
#pragma unroll
        for (int i = 0; i < 4; ++i) {
            *(u16x8*)&As[str + i * 32][sc] = areg[i];
            *(u16x8*)&Bs[str + i * 32][sc] = breg[i];
        }
        __syncthreads();
        if (k0 + 64 < K) {
#pragma unroll
            for (int i = 0; i < 4; ++i) {
                areg[i] = *(const u16x8*)&A[(size_t)(n0 + str + i * 32) * K + k0 + 64 + sc];
                breg[i] = *(const u16x8*)&B[(size_t)(j0 + str + i * 32) * K + k0 + 64 + sc];
            }
        }
        __builtin_amdgcn_s_setprio(1);
#pragma unroll
        for (int kc = 0; kc < 2; ++kc) {
            bf16x8 af[4], bfr[4];
#pragma unroll
            for (int mf = 0; mf < 4; ++mf)
                af[mf] = *(const bf16x8*)&As[wr * 64 + mf * 16 + li][kc * 32 + lg * 8];
#pragma unroll
            for (int nf = 0; nf < 4; ++nf)
                bfr[nf] = *(const bf16x8*)&Bs[wc * 64 + nf * 16 + li][kc * 32 + lg * 8];
#pragma unroll
            for (int mf = 0; mf < 4; ++mf)
#pragma unroll
                for (int nf = 0; nf < 4; ++nf)
                    acc[mf][nf] = __builtin_amdgcn_mfma_f32_16x16x32_bf16(af[mf], bfr[nf], acc[mf][nf], 0, 0, 0);
        }
        __builtin_amdgcn_s_setprio(0);
    }
    // epilogue: C row = n0+wr*64+mf*16+lg*4+r, col = j0+wc*64+nf*16+li
#pragma unroll
    for (int mf = 0; mf < 4; ++mf) {
#pragma unroll
        for (int r = 0; r < 4; ++r) {
            const int row = n0 + wr * 64 + mf * 16 + lg * 4 + r;
#pragma unroll
            for (int nf = 0; nf < 4; ++nf) {
                const int col = j0 + wc * 64 + nf * 16 + li;
                float v = acc[mf][nf][r] * scale;
                if (ADD) v += addv[(size_t)row * N + col];
                if (BF16OUT) ((unsigned short*)Cv)[(size_t)row * N + col] = f2bf(v);
                else         ((float*)Cv)[(size_t)row * N + col] = v;
            }
        }
    }
}

// ---------------------------------------------------------------- MFMA flash attention, K-split
__global__ __launch_bounds__(256) void attn_mfma(const unsigned short* __restrict__ Qb,
                                                 const unsigned short* __restrict__ Kb,
                                                 const unsigned short* __restrict__ Vtb,
                                                 const int* __restrict__ prows,
                                                 const int* __restrict__ pcols,
                                                 const float* __restrict__ dist_bias,
                                                 unsigned short* __restrict__ Opart,
                                                 float* __restrict__ Mp,
                                                 float* __restrict__ Lp) {
    const int h  = blockIdx.y;
    const int n0 = blockIdx.x * BQ;
    const int sp = blockIdx.z;
    __shared__ unsigned short Ks[BK][136];
    __shared__ unsigned short Vts[HDIM][72];
    __shared__ unsigned short Ps[BQ][72];
    __shared__ float biasT[3043];
    __shared__ int krs[BK], kcs[BK];

    const int t    = threadIdx.x;
    const int lane = t & 63;
    const int lg   = lane >> 4;
    const int li   = lane & 15;
    const int qbase = (t >> 6) * 16;

    for (int idx = t; idx < 3043; idx += 256) {
        float d  = sqrtf((float)idx);
        int bin  = (int)(log1pf(d) * (31.0f / 4.0529789877f));
        bin = bin > 31 ? 31 : bin;
        biasT[idx] = dist_bias[h * NBINS + bin];
    }

    bf16x8 qf[4];
    {
        const unsigned short* qptr = &Qb[(size_t)(n0 + qbase + li) * DMODEL + h * HDIM];
#pragma unroll
        for (int kc = 0; kc < 4; ++kc)
            qf[kc] = *(const bf16x8*)&qptr[kc * 32 + lg * 8];
    }
    int qr_[4], qc_[4];
#pragma unroll
    for (int r = 0; r < 4; ++r) {
        qr_[r] = prows[n0 + qbase + lg * 4 + r];
        qc_[r] = pcols[n0 + qbase + lg * 4 + r];
    }
    float m_[4] = {-1e30f, -1e30f, -1e30f, -1e30f};
    float l_[4] = {0.f, 0.f, 0.f, 0.f};
    f32x4 accO[8];
#pragma unroll
    for (int dt = 0; dt < 8; ++dt) accO[dt] = (f32x4){0.f, 0.f, 0.f, 0.f};

    u16x8 kreg[4], vreg[4];
    int krreg = 0, kcreg = 0;
    const int ktr = t >> 4, kch = (t & 15) * 8;
    const int vtr = t >> 3, vch = (t & 7) * 8;

    int m0 = sp * KV_PER_SPLIT;
    {
#pragma unroll
        for (int i = 0; i < 4; ++i)
            kreg[i] = *(const u16x8*)&Kb[(size_t)(m0 + ktr + i * 16) * DMODEL + h * HDIM + kch];
#pragma unroll
        for (int i = 0; i < 4; ++i)
            vreg[i] = *(const u16x8*)&Vtb[(size_t)(h * HDIM + vtr + i * 32) * N_TOK + m0 + vch];
        if (t < BK) { krreg = prows[m0 + t]; kcreg = pcols[m0 + t]; }
    }

    for (int kb = 0; kb < KV_PER_SPLIT / BK; ++kb, m0 += BK) {
        __syncthreads();
#pragma unroll
        for (int i = 0; i < 4; ++i) *(u16x8*)&Ks[ktr + i * 16][kch] = kreg[i];
#pragma unroll
        for (int i = 0; i < 4; ++i) *(u16x8*)&Vts[vtr + i * 32][vch] = vreg[i];
        if (t < BK) { krs[t] = krreg; kcs[t] = kcreg; }
        __syncthreads();

        if (kb + 1 < KV_PER_SPLIT / BK) {
            const int m1 = m0 + BK;
#pragma unroll
            for (int i = 0; i < 4; ++i)
                kreg[i] = *(const u16x8*)&Kb[(size_t)(m1 + ktr + i * 16) * DMODEL + h * HDIM + kch];
#pragma unroll
            for (int i = 0; i < 4; ++i)
                vreg[i] = *(const u16x8*)&Vtb[(size_t)(h * HDIM + vtr + i * 32) * N_TOK + m1 + vch];
            if (t < BK) { krreg = prows[m1 + t]; kcreg = pcols[m1 + t]; }
        }

        f32x4 s[4];
        __builtin_amdgcn_s_setprio(1);
#pragma unroll
        for (int jt = 0; jt < 4; ++jt) {
            f32x4 acc = {0.f, 0.f, 0.f, 0.f};
#pragma unroll
            for (int kc = 0; kc < 4; ++kc) {
                bf16x8 kf = *(const bf16x8*)&Ks[jt * 16 + li][kc * 32 + lg * 8];
                acc = __builtin_amdgcn_mfma_f32_16x16x32_bf16(qf[kc], kf, acc, 0, 0, 0);
            }
            s[jt] = acc;
        }
        __builtin_amdgcn_s_setprio(0);

        float p[4][4];
#pragma unroll
        for (int jt = 0; jt < 4; ++jt) {
            int krj = krs[jt * 16 + li], kcj = kcs[jt * 16 + li];
#pragma unroll
            for (int r = 0; r < 4; ++r) {
                int dr = qr_[r] - krj, dc = qc_[r] - kcj;
                p[jt][r] = s[jt][r] + biasT[dr * dr + dc * dc];
            }
        }

#pragma unroll
        for (int r = 0; r < 4; ++r) {
            float mx = fmaxf(fmaxf(p[0][r], p[1][r]), fmaxf(p[2][r], p[3][r]));
            mx = fmaxf(mx, __shfl_xor(mx, 1));
            mx = fmaxf(mx, __shfl_xor(mx, 2));
            mx = fmaxf(mx, __shfl_xor(mx, 4));
            mx = fmaxf(mx, __shfl_xor(mx, 8));
            float mnew  = fmaxf(m_[r], mx);
            float alpha = __expf(m_[r] - mnew);
            float rs = 0.f;
#pragma unroll
            for (int jt = 0; jt < 4; ++jt) { p[jt][r] = __expf(p[jt][r] - mnew); rs += p[jt][r]; }
            rs += __shfl_xor(rs, 1);
            rs += __shfl_xor(rs, 2);
            rs += __shfl_xor(rs, 4);
            rs += __shfl_xor(rs, 8);
            l_[r] = l_[r] * alpha + rs;
            m_[r] = mnew;
#pragma unroll
            for (int dt = 0; dt < 8; ++dt) accO[dt][r] *= alpha;
        }

#pragma unroll
        for (int r = 0; r < 4; ++r)
#pragma unroll
            for (int jt = 0; jt < 4; ++jt)
                Ps[qbase + lg * 4 + r][jt * 16 + li] = f2bf(p[jt][r]);

        bf16x8 pf0 = *(const bf16x8*)&Ps[qbase + li][lg * 8];
        bf16x8 pf1 = *(const bf16x8*)&Ps[qbase + li][32 + lg * 8];
        __builtin_amdgcn_s_setprio(1);
#pragma unroll
        for (int dt = 0; dt < 8; ++dt) {
            bf16x8 vf0 = *(const bf16x8*)&Vts[dt * 16 + li][lg * 8];
            bf16x8 vf1 = *(const bf16x8*)&Vts[dt * 16 + li][32 + lg * 8];
            accO[dt] = __builtin_amdgcn_mfma_f32_16x16x32_bf16(pf0, vf0, accO[dt], 0, 0, 0);
            accO[dt] = __builtin_amdgcn_mfma_f32_16x16x32_bf16(pf1, vf1, accO[dt], 0, 0, 0);
        }
        __builtin_amdgcn_s_setprio(0);
    }

#pragma unroll
    for (int r = 0; r < 4; ++r) {
        float inv = 1.0f / l_[r];
        int row = n0 + qbase + lg * 4 + r;
#pragma unroll
        for (int dt = 0; dt < 8; ++dt)
            Opart[(size_t)sp * N_TOK * DMODEL + (size_t)row * DMODEL + h * HDIM + dt * 16 + li] =
                f2bf(accO[dt][r] * inv);
        if (li == 0) {
            Mp[((size_t)sp * NHEAD + h) * N_TOK + row] = m_[r];
            Lp[((size_t)sp * NHEAD + h) * N_TOK + row] = l_[r];
        }
    }
}

// ---------------------------------------------------------------- combine K-split partials -> bf16
__global__ __launch_bounds__(256) void combine_kernel(const unsigned short* __restrict__ Opart,
                                                      const float* __restrict__ Mp,
                                                      const float* __restrict__ Lp,
                                                      unsigned short* __restrict__ outbf) {
    int n = blockIdx.x, t = threadIdx.x;
#pragma unroll
    for (int d0 = t; d0 < DMODEL; d0 += 256) {
        int h = d0 >> 7;
        float m1 = Mp[(size_t)h * N_TOK + n];
        float m2 = Mp[((size_t)NHEAD + h) * N_TOK + n];
        float l1 = Lp[(size_t)h * N_TOK + n];
        float l2 = Lp[((size_t)NHEAD + h) * N_TOK + n];
        float m  = fmaxf(m1, m2);
        float a1 = __expf(m1 - m) * l1, a2 = __expf(m2 - m) * l2;
        float inv = 1.0f / (a1 + a2);
        float o1 = bf2f(Opart[(size_t)n * DMODEL + d0]);
        float o2 = bf2f(Opart[(size_t)N_TOK * DMODEL + (size_t)n * DMODEL + d0]);
        outbf[(size_t)n * DMODEL + d0] = f2bf((a1 * o1 + a2 * o2) * inv);
    }
}

// ---------------------------------------------------------------- LN + gated residual
__global__ __launch_bounds__(256) void final_kernel(const float* __restrict__ o,
                                                    const float* __restrict__ vh,
                                                    const float* __restrict__ lnw,
                                                    const float* __restrict__ lnb,
                                                    const float* __restrict__ gparam,
                                                    float* __restrict__ out) {
    int n = blockIdx.x, t = threadIdx.x;
    size_t base = (size_t)n * DMODEL;
    float x0 = o[base + t], x1 = o[base + t + 256];
    __shared__ float red[4];
    float v = x0 + x1;
#pragma unroll
    for (int off = 32; off > 0; off >>= 1) v += __shfl_down(v, off, 64);
    if ((t & 63) == 0) red[t >> 6] = v;
    __syncthreads();
    float mu = (red[0] + red[1] + red[2] + red[3]) * (1.0f / 512.0f);
    __syncthreads();
    float d0 = x0 - mu, d1 = x1 - mu;
    v = d0 * d0 + d1 * d1;
#pragma unroll
    for (int off = 32; off > 0; off >>= 1) v += __shfl_down(v, off, 64);
    if ((t & 63) == 0) red[t >> 6] = v;
    __syncthreads();
    float var  = (red[0] + red[1] + red[2] + red[3]) * (1.0f / 512.0f);
    float rstd = rsqrtf(var + 1e-5f);
    float gamma = log1pf(expf(gparam[0]));
    out[base + t]       = vh[base + t]       + gamma * (d0 * rstd * lnw[t]       + lnb[t]);
    out[base + t + 256] = vh[base + t + 256] + gamma * (d1 * rstd * lnw[t + 256] + lnb[t + 256]);
}

// ---------------------------------------------------------------- launch
extern "C" void kernel_launch(void* const* d_in, const int* in_sizes, int n_in,
                              void* d_out, int out_size, void* d_ws, size_t ws_size,
                              hipStream_t stream) {
    const float* vision_h  = (const float*)d_in[0];
    const int*   prows     = (const int*)d_in[1];
    const int*   pcols     = (const int*)d_in[2];
    const float* pos_w     = (const float*)d_in[3];
    const float* q_w       = (const float*)d_in[4];
    const float* k_w       = (const float*)d_in[5];
    const float* v_w       = (const float*)d_in[6];
    const float* out_w     = (const float*)d_in[7];
    const float* dist_bias = (const float*)d_in[8];
    const float* gamma_p   = (const float*)d_in[9];
    const float* ln_w      = (const float*)d_in[10];
    const float* ln_b      = (const float*)d_in[11];
    float* out = (float*)d_out;
    char* base = (char*)d_ws;

    const size_t MB = 1024 * 1024;
    unsigned short* pe_bf   = (unsigned short*)(base + 0);        // 4 MB
    unsigned short* vh_bf   = (unsigned short*)(base + 4  * MB);  // 4 MB
    unsigned short* hpos_bf = (unsigned short*)(base + 8  * MB);  // 4 MB
    unsigned short* Qb      = (unsigned short*)(base + 12 * MB);  // 4 MB
    unsigned short* Kb      = (unsigned short*)(base + 16 * MB);  // 4 MB
    unsigned short* Vtb     = (unsigned short*)(base + 20 * MB);  // 4 MB
    unsigned short* Opart   = (unsigned short*)(base + 24 * MB);  // 8 MB (2 splits)
    float*          Mp      = (float*)(base + 32 * MB);           // 128 KB
    float*          Lp      = (float*)(base + 32 * MB + 131072);  // 128 KB
    unsigned short* wbf     = (unsigned short*)(base + 32 * MB + 262144);  // 2.5 MB
    unsigned short* attn_bf = pe_bf;                 // reuse (pe dead after hpos)
    float*          ob      = (float*)(base + 24 * MB);  // reuse Opart (dead after combine)

    unsigned short* w_pos = wbf;
    unsigned short* w_q   = wbf + 1 * DMODEL * DMODEL;
    unsigned short* w_k   = wbf + 2 * DMODEL * DMODEL;
    unsigned short* w_v   = wbf + 3 * DMODEL * DMODEL;
    unsigned short* w_o   = wbf + 4 * DMODEL * DMODEL;

    const float qscale = 0.08838834764831845f;  // 1/sqrt(128)

    pe_prep<<<N_TOK, 256, 0, stream>>>(prows, pcols, vision_h, pe_bf, vh_bf);
    wconv5<<<dim3(256, 5), 256, 0, stream>>>(pos_w, q_w, k_w, v_w, out_w, wbf);
    // h_pos = pe @ pos_w^T + vision_h  (bf16 out)
    gemm_mfma<true,  true ><<<dim3(32, 4), 256, 0, stream>>>(pe_bf, w_pos, vision_h, hpos_bf,
                                                             N_TOK, DMODEL, DMODEL, 1.0f);
    // Q (scaled), K
    gemm_mfma<false, true ><<<dim3(32, 4), 256, 0, stream>>>(hpos_bf, w_q, nullptr, Qb,
                                                             N_TOK, DMODEL, DMODEL, qscale);
    gemm_mfma<false, true ><<<dim3(32, 4), 256, 0, stream>>>(hpos_bf, w_k, nullptr, Kb,
                                                             N_TOK, DMODEL, DMODEL, 1.0f);
    // Vt = v_w @ vision_h^T : A = v_w [512][512], B = vh_bf [4096][512], C = [512][4096]
    gemm_mfma<false, true ><<<dim3(4, 32), 256, 0, stream>>>(w_v, vh_bf, nullptr, Vtb,
                                                             DMODEL, N_TOK, DMODEL, 1.0f);
    attn_mfma<<<dim3(N_TOK / BQ, NHEAD, NSPLIT), 256, 0, stream>>>(Qb, Kb, Vtb, prows, pcols,
                                                                   dist_bias, Opart, Mp, Lp);
    combine_kernel<<<N_TOK, 256, 0, stream>>>(Opart, Mp, Lp, attn_bf);
    // o = attn @ out_w^T (f32 out)
    gemm_mfma<false, false><<<dim3(32, 4), 256, 0, stream>>>(attn_bf, w_o, nullptr, ob,
                                                             N_TOK, DMODEL, DMODEL, 1.0f);
    final_kernel<<<N_TOK, 256, 0, stream>>>(ob, vision_h, ln_w, ln_b, gamma_p, out);
}